// Round 1
// baseline (234.760 us; speedup 1.0000x reference)
//
#include <hip/hip_runtime.h>
#include <cmath>

// PRNNCell: B=64, I=512, H=1024, D=1536
//   x = concat(inputs, hidden)                       (B, D)
//   new_hidden = tanh(einsum('bd,bhd->bh', x, wih) + bih)
//   new_wih = wih + y*x*Wa + x*Wb + y*Wc + Wd        (y = new_hidden[b,h])
//   (dop is computed in the reference but never returned -> dead code, skipped)
//
// Strategy: one wave per (b,h) row of D=1536 floats. Lane i holds 6 float4 of
// x and of wih in registers; wave-reduce the dot product, tanh, then compute
// the update from registers so wih is fetched from HBM exactly once.

#define BB 64
#define II 512
#define HH 1024
#define DD 1536

__global__ __launch_bounds__(256) void prnn_fused(
    const float* __restrict__ inputs,   // B x I
    const float* __restrict__ hidden,   // B x H
    const float* __restrict__ wih,      // B x H x D
    const float* __restrict__ Wa,       // H x D
    const float* __restrict__ Wb,
    const float* __restrict__ Wc,
    const float* __restrict__ Wd,
    const float* __restrict__ bih,      // H
    float* __restrict__ out_h,          // B x H
    float* __restrict__ out_w)          // B x H x D
{
    constexpr int K = (DD / 4) / 64;    // 6 float4 per lane
    const int wid  = threadIdx.x >> 6;
    const int lane = threadIdx.x & 63;
    const int r = blockIdx.x * 4 + wid; // row id = b*H + h, 0..65535
    const int b = r >> 10;              // r / H
    const int h = r & (HH - 1);

    const float4* __restrict__ wrow = (const float4*)(wih + (size_t)r * DD);
    const float4* __restrict__ arow = (const float4*)(Wa + (size_t)h * DD);
    const float4* __restrict__ brow = (const float4*)(Wb + (size_t)h * DD);
    const float4* __restrict__ crow = (const float4*)(Wc + (size_t)h * DD);
    const float4* __restrict__ drow = (const float4*)(Wd + (size_t)h * DD);
    const float4* __restrict__ xin  = (const float4*)(inputs + (size_t)b * II);
    const float4* __restrict__ xhi  = (const float4*)(hidden + (size_t)b * HH);

    float4 xv[K], wv[K];
    float dot = 0.f;
#pragma unroll
    for (int k = 0; k < K; ++k) {
        const int j = lane + 64 * k;    // float4 index within the row, 0..383
        // x float4: j < 128 -> inputs (d<512), else hidden. k is compile-time.
        xv[k] = (k < 2) ? xin[j] : xhi[j - 128];
        wv[k] = wrow[j];
        dot += xv[k].x * wv[k].x + xv[k].y * wv[k].y
             + xv[k].z * wv[k].z + xv[k].w * wv[k].w;
    }

    // 64-lane butterfly reduce
#pragma unroll
    for (int off = 32; off >= 1; off >>= 1)
        dot += __shfl_xor(dot, off, 64);

    const float y = tanhf(dot + bih[h]);
    if (lane == 0) out_h[r] = y;

    float4* __restrict__ orow = (float4*)(out_w + (size_t)r * DD);
#pragma unroll
    for (int k = 0; k < K; ++k) {
        const int j = lane + 64 * k;
        const float4 a  = arow[j];
        const float4 b2 = brow[j];
        const float4 c  = crow[j];
        const float4 d  = drow[j];
        float4 o;
        o.x = wv[k].x + xv[k].x * fmaf(y, a.x, b2.x) + fmaf(y, c.x, d.x);
        o.y = wv[k].y + xv[k].y * fmaf(y, a.y, b2.y) + fmaf(y, c.y, d.y);
        o.z = wv[k].z + xv[k].z * fmaf(y, a.z, b2.z) + fmaf(y, c.z, d.z);
        o.w = wv[k].w + xv[k].w * fmaf(y, a.w, b2.w) + fmaf(y, c.w, d.w);
        orow[j] = o;
    }
}

extern "C" void kernel_launch(void* const* d_in, const int* in_sizes, int n_in,
                              void* d_out, int out_size, void* d_ws, size_t ws_size,
                              hipStream_t stream) {
    const float* inputs = (const float*)d_in[0];
    const float* hidden = (const float*)d_in[1];
    const float* wih    = (const float*)d_in[2];
    const float* Wa     = (const float*)d_in[3];
    const float* Wb     = (const float*)d_in[4];
    const float* Wc     = (const float*)d_in[5];
    const float* Wd     = (const float*)d_in[6];
    const float* bih    = (const float*)d_in[7];
    // d_in[8] = W_dop, d_in[9] = b_dop: dead code in the reference, unused.

    float* out   = (float*)d_out;
    float* out_h = out;                    // B*H floats
    float* out_w = out + (size_t)BB * HH;  // B*H*D floats

    dim3 grid((BB * HH) / 4), block(256);
    prnn_fused<<<grid, block, 0, stream>>>(inputs, hidden, wih, Wa, Wb, Wc, Wd,
                                           bih, out_h, out_w);
}

// Round 3
// 162.878 us; speedup vs baseline: 1.4413x; 1.4413x over previous
//
#include <hip/hip_runtime.h>
#include <cmath>

// PRNNCell: B=64, I=512, H=1024, D=1536
//   x = concat(inputs, hidden)                       (B, D)
//   new_hidden = tanh(einsum('bd,bhd->bh', x, wih) + bih)
//   new_wih = wih + y*x*Wa + x*Wb + y*Wc + Wd        (y = new_hidden[b,h])
//   (dop in the reference is dead code -> skipped)
//
// R3 = R2 with native vector type for nontemporal builtins.
// One block per h (1024 blocks x 512 thr). Wa..d[h,:] staged in 24 KB LDS
// once. Each of 8 waves owns 8 batch rows: stream wih row from HBM once
// (nontemporal), dot+reduce+tanh, update from LDS/regs, nontemporal store.
// x is re-read in the update phase (L1/L2-hot, unique 393 KB) to keep VGPR low.

#define BB 64
#define II 512
#define HH 1024
#define DD 1536
#define NF4 (DD / 4)          // 384 vec4 per row
#define THREADS 512
#define PER_WAVE (BB / 8)     // 8 rows per wave

typedef float f4 __attribute__((ext_vector_type(4)));

__global__ __launch_bounds__(THREADS) void prnn_fused(
    const float* __restrict__ inputs,   // B x I
    const float* __restrict__ hidden,   // B x H
    const float* __restrict__ wih,      // B x H x D
    const float* __restrict__ Wa,       // H x D
    const float* __restrict__ Wb,
    const float* __restrict__ Wc,
    const float* __restrict__ Wd,
    const float* __restrict__ bih,      // H
    float* __restrict__ out_h,          // B x H
    float* __restrict__ out_w)          // B x H x D
{
    __shared__ f4 sA[NF4], sB[NF4], sC[NF4], sD[NF4];   // 24 KB

    const int h    = blockIdx.x;
    const int tid  = threadIdx.x;
    const int lane = tid & 63;
    const int wid  = tid >> 6;

    if (tid < NF4) {
        sA[tid] = ((const f4*)(Wa + (size_t)h * DD))[tid];
        sB[tid] = ((const f4*)(Wb + (size_t)h * DD))[tid];
        sC[tid] = ((const f4*)(Wc + (size_t)h * DD))[tid];
        sD[tid] = ((const f4*)(Wd + (size_t)h * DD))[tid];
    }
    const float bh = bih[h];
    __syncthreads();

    for (int i = 0; i < PER_WAVE; ++i) {
        const int b    = wid * PER_WAVE + i;            // wave-uniform
        const size_t r = (size_t)b * HH + h;
        const f4* __restrict__ wrow = (const f4*)(wih + r * DD);
        const f4* __restrict__ xin  = (const f4*)(inputs + (size_t)b * II);
        const f4* __restrict__ xhi  = (const f4*)(hidden + (size_t)b * HH);

        // Phase 1: stream wih row into regs, dot with x (x not kept live).
        f4 wv[6];
        float dot = 0.f;
#pragma unroll
        for (int k = 0; k < 6; ++k) {
            const int j = lane + 64 * k;                // 0..383
            wv[k] = __builtin_nontemporal_load(&wrow[j]);
            const f4 xk = (k < 2) ? xin[j] : xhi[j - 128];
            dot += xk.x * wv[k].x + xk.y * wv[k].y
                 + xk.z * wv[k].z + xk.w * wv[k].w;
        }
#pragma unroll
        for (int off = 32; off >= 1; off >>= 1)
            dot += __shfl_xor(dot, off, 64);
        const float y = tanhf(dot + bh);
        if (lane == 0) out_h[r] = y;

        // Phase 2: update from LDS + regs; x re-read (cache-hot).
        f4* __restrict__ orow = (f4*)(out_w + r * DD);
#pragma unroll
        for (int k = 0; k < 6; ++k) {
            const int j = lane + 64 * k;
            const f4 xk = (k < 2) ? xin[j] : xhi[j - 128];
            const f4 a  = sA[j];
            const f4 b2 = sB[j];
            const f4 c  = sC[j];
            const f4 d  = sD[j];
            f4 o;
            o.x = wv[k].x + xk.x * fmaf(y, a.x, b2.x) + fmaf(y, c.x, d.x);
            o.y = wv[k].y + xk.y * fmaf(y, a.y, b2.y) + fmaf(y, c.y, d.y);
            o.z = wv[k].z + xk.z * fmaf(y, a.z, b2.z) + fmaf(y, c.z, d.z);
            o.w = wv[k].w + xk.w * fmaf(y, a.w, b2.w) + fmaf(y, c.w, d.w);
            __builtin_nontemporal_store(o, &orow[j]);
        }
    }
}

extern "C" void kernel_launch(void* const* d_in, const int* in_sizes, int n_in,
                              void* d_out, int out_size, void* d_ws, size_t ws_size,
                              hipStream_t stream) {
    const float* inputs = (const float*)d_in[0];
    const float* hidden = (const float*)d_in[1];
    const float* wih    = (const float*)d_in[2];
    const float* Wa     = (const float*)d_in[3];
    const float* Wb     = (const float*)d_in[4];
    const float* Wc     = (const float*)d_in[5];
    const float* Wd     = (const float*)d_in[6];
    const float* bih    = (const float*)d_in[7];
    // d_in[8] = W_dop, d_in[9] = b_dop: dead code in the reference, unused.

    float* out   = (float*)d_out;
    float* out_h = out;                    // B*H floats
    float* out_w = out + (size_t)BB * HH;  // B*H*D floats

    dim3 grid(HH), block(THREADS);
    prnn_fused<<<grid, block, 0, stream>>>(inputs, hidden, wih, Wa, Wb, Wc, Wd,
                                           bih, out_h, out_w);
}